// Round 7
// baseline (1773.989 us; speedup 1.0000x reference)
//
#include <hip/hip_runtime.h>
#include <hip/hip_bf16.h>
#include <stdint.h>

// RWKV7-like block: B=4 T=2048 D=1024 NH=16 HD=64.
// Inputs fp32 (documented order x,Wr,Wk,Wv,Ww,Wo). OUTPUT IS FP32 (reference
// returns fp32; prior rounds wrongly wrote packed bf16 -> decorrelated absmax).
//
// Algebra (exact): out_t[i] = r[i]*S[i], S[i] <- w[i]*S[i] + v[i]*Ksum,
//   Ksum[b,h,t] = x_t . (sum_j Wk[h*64+j,:])  -> k never materialized.
// Cross-validated: MFMA GEMM == fp32 vgemm (R3==R4 bit-identical);
// collapsed scan == literal 64x64 scan (R4~R5).
//
// ws (~40.6 MiB): x_c bf16 16M | W_c bf16 8M (Wr,Wv,Ww,Wo) | v_so bf16 16M
//   | ksum fp32 512K | wks fp32 64K
// d_out (fp32, 32 MiB) doubles as scratch for r (bf16, [0,16M)) and
// w (bf16, [16M,32M)) - both dead after scan, before out_gemm writes d_out.

#define BB 4
#define TT 2048
#define DD 1024
#define NHH 16
#define HDD 64

using bf16 = __hip_bfloat16;
typedef __attribute__((ext_vector_type(8))) short bfrag8;   // 8 x bf16
typedef __attribute__((ext_vector_type(4))) float f32x4;

__device__ __forceinline__ void async_ld16(const bf16* g, bf16* l) {
  __builtin_amdgcn_global_load_lds(
      (const __attribute__((address_space(1))) uint32_t*)g,
      (__attribute__((address_space(3))) uint32_t*)l, 16, 0, 0);
}

__device__ __forceinline__ float sigm(float x) { return 1.0f / (1.0f + expf(-x)); }
__device__ __forceinline__ float bf2f(bf16 h) {
  unsigned short u = *reinterpret_cast<unsigned short*>(&h);
  return __uint_as_float((unsigned)u << 16);
}
__device__ __forceinline__ unsigned short f2bfbits(float f) {
  bf16 b = __float2bfloat16(f);
  return *reinterpret_cast<unsigned short*>(&b);
}

// ---- fp32 -> bf16 conversion: x (2097152 float4 groups) + Wr,Wv,Ww,Wo ----
__global__ __launch_bounds__(256)
void convert_kernel(const float* __restrict__ x,
                    const float* __restrict__ Wr, const float* __restrict__ Wv,
                    const float* __restrict__ Ww, const float* __restrict__ Wo,
                    bf16* __restrict__ x_c, bf16* __restrict__ W_c)
{
  const long g = (long)blockIdx.x * 256 + threadIdx.x;   // < 3145728
  const float* src; bf16* dst; long off4;
  if (g < 2097152) { src = x; dst = x_c; off4 = g; }
  else {
    long gg = g - 2097152;
    int wsel = (int)(gg >> 18);           // 262144 groups per weight
    off4 = gg & 262143;
    src = (wsel == 0) ? Wr : (wsel == 1) ? Wv : (wsel == 2) ? Ww : Wo;
    dst = W_c + (long)wsel * 1048576;
  }
  float4 f = reinterpret_cast<const float4*>(src)[off4];
  ushort4 pk;
  pk.x = f2bfbits(f.x); pk.y = f2bfbits(f.y);
  pk.z = f2bfbits(f.z); pk.w = f2bfbits(f.w);
  reinterpret_cast<ushort4*>(dst)[off4] = pk;
}

// ---- wks[h][c] = sum_{j<64} Wk[h*64+j][c]  (fp32) ----
__global__ __launch_bounds__(256)
void wksum_kernel(const float* __restrict__ Wk, float* __restrict__ wks)
{
  const int gid = blockIdx.x * 256 + threadIdx.x;   // 16384
  const int h = gid >> 10, c = gid & 1023;
  float s = 0.0f;
  for (int j = 0; j < 64; ++j)
    s += Wk[(long)((h << 6) + j) * 1024 + c];
  wks[gid] = s;
}

// ---- MFMA GEMM mainloop (m97 structure; cross-validated R3==R4) ----
// C[m,n] = sum_k A[m,k]*W[n,k]; 128x128 tile, BK=32, 4 waves, 4x4 16x16x32.
__device__ __forceinline__ void gemm_mainloop(
    const bf16* __restrict__ A, const bf16* __restrict__ W,
    int blockM, int blockN, bf16* a_sh, bf16* b_sh, f32x4 acc[4][4])
{
  const int tid    = threadIdx.x;
  const int wave   = tid >> 6;
  const int lane   = tid & 63;
  const int lane15 = lane & 15;
  const int quad   = lane >> 4;
  const int waveM  = wave >> 1;
  const int waveN  = wave & 1;
  const int s_row  = (wave << 5) + (lane >> 2);
  const int s_col  = (lane & 3) << 3;

  const bf16* gA = A + ((long)(blockM * 128) + s_row) * 1024 + s_col;
  const bf16* gW = W + ((long)(blockN * 128) + s_row) * 1024 + s_col;
  bf16* la = a_sh + wave * 1024;   // wave-uniform base; HW scatters +lane*16B
  bf16* lb = b_sh + wave * 1024;

  for (int k0 = 0; k0 < 1024; k0 += 32) {
    async_ld16(gA + k0,            la);
    async_ld16(gA + k0 + 16*1024,  la + 512);
    async_ld16(gW + k0,            lb);
    async_ld16(gW + k0 + 16*1024,  lb + 512);
    __syncthreads();
    bfrag8 af[4], bfv[4];
#pragma unroll
    for (int mi = 0; mi < 4; ++mi)
      af[mi] = *reinterpret_cast<const bfrag8*>(a_sh + (waveM*64 + mi*16 + lane15)*32 + quad*8);
#pragma unroll
    for (int ni = 0; ni < 4; ++ni)
      bfv[ni] = *reinterpret_cast<const bfrag8*>(b_sh + (waveN*64 + ni*16 + lane15)*32 + quad*8);
#pragma unroll
    for (int mi = 0; mi < 4; ++mi)
#pragma unroll
      for (int ni = 0; ni < 4; ++ni)
        acc[mi][ni] = __builtin_amdgcn_mfma_f32_16x16x32_bf16(af[mi], bfv[ni], acc[mi][ni], 0, 0, 0);
    __syncthreads();
  }
}

// mode 0: r = sigm(x Wr^T)   1: v = x Wv^T   2: w = sigm(x Ww^T)*0.99
__global__ __launch_bounds__(256, 2)
void proj_kernel(const bf16* __restrict__ X, const bf16* __restrict__ W_c,
                 bf16* __restrict__ r_out, bf16* __restrict__ v_out,
                 bf16* __restrict__ w_out)
{
  __shared__ __align__(16) bf16 a_sh[128*32];
  __shared__ __align__(16) bf16 b_sh[128*32];
  const int mode = blockIdx.z;
  const bf16* W = W_c + (long)mode * 1048576;   // Wr, Wv, Ww
  f32x4 acc[4][4] = {};
  gemm_mainloop(X, W, blockIdx.y, blockIdx.x, a_sh, b_sh, acc);

  const int tid = threadIdx.x;
  const int wave = tid >> 6, lane = tid & 63;
  const int lane15 = lane & 15, quad = lane >> 4;
  const int waveM = wave >> 1, waveN = wave & 1;
  const int m_base = blockIdx.y * 128 + waveM * 64;
  const int n_base = blockIdx.x * 128 + waveN * 64;   // C/D: row=quad*4+reg, col=lane15
  bf16* outp = (mode == 0) ? r_out : (mode == 1) ? v_out : w_out;
#pragma unroll
  for (int mi = 0; mi < 4; ++mi)
#pragma unroll
    for (int ni = 0; ni < 4; ++ni)
#pragma unroll
      for (int r = 0; r < 4; ++r) {
        float val = acc[mi][ni][r];
        if (mode == 0) val = sigm(val);
        else if (mode == 2) val = sigm(val) * 0.99f;
        int m = m_base + mi*16 + quad*4 + r;
        int n = n_base + ni*16 + lane15;
        outp[(long)m * DD + n] = __float2bfloat16(val);
      }
}

// ---- ksum[b,h,t] = x_row(m) . wks[h] ----
__global__ __launch_bounds__(256)
void ksum_kernel(const bf16* __restrict__ X, const float* __restrict__ wks,
                 float* __restrict__ ksum)
{
  __shared__ __align__(8) bf16 xs[DD];
  const int m = blockIdx.x;
  const int tid = threadIdx.x;
  *reinterpret_cast<ushort4*>(xs + tid*4) =
      *reinterpret_cast<const ushort4*>(X + (long)m * DD + tid*4);
  __syncthreads();
  const int wave = tid >> 6, lane = tid & 63;
  const int b = m >> 11, t = m & (TT - 1);
#pragma unroll
  for (int hi = 0; hi < 4; ++hi) {
    const int h = wave * 4 + hi;
    float acc = 0.0f;
#pragma unroll
    for (int i = 0; i < 16; ++i) {
      const int c = lane + (i << 6);
      acc += bf2f(xs[c]) * wks[h * DD + c];
    }
#pragma unroll
    for (int msk = 1; msk <= 32; msk <<= 1) acc += __shfl_xor(acc, msk);
    if (lane == 0) ksum[((long)(b * NHH + h)) * TT + t] = acc;
  }
}

// ---- collapsed scan: one wave per (b,h), lane owns a channel. v_so: v in,
// scan-out out (each address read-as-v 8 steps before written, same thread).
__global__ __launch_bounds__(64, 1)
void scan_kernel(const bf16* __restrict__ r_buf, bf16* v_so,
                 const bf16* __restrict__ w_buf, const float* __restrict__ ksum)
{
  const int bh = blockIdx.x;
  const int b = bh >> 4, h = bh & 15;
  const int i = threadIdx.x;
  const float* ks = ksum + (long)bh * TT;
  const long base = (long)b * TT * DD + h * HDD + i;

  float rv[2][8], vv[2][8], wv[2][8], kk[2][8];
  auto load8 = [&](int buf, int t0) {
#pragma unroll
    for (int u = 0; u < 8; ++u) {
      long idx = base + (long)(t0 + u) * DD;
      rv[buf][u] = bf2f(r_buf[idx]);
      vv[buf][u] = bf2f(v_so[idx]);
      wv[buf][u] = bf2f(w_buf[idx]);
    }
    float4 ka = *reinterpret_cast<const float4*>(ks + t0);
    float4 kb = *reinterpret_cast<const float4*>(ks + t0 + 4);
    kk[buf][0] = ka.x; kk[buf][1] = ka.y; kk[buf][2] = ka.z; kk[buf][3] = ka.w;
    kk[buf][4] = kb.x; kk[buf][5] = kb.y; kk[buf][6] = kb.z; kk[buf][7] = kb.w;
  };

  load8(0, 0);
  float s = 0.0f;
  for (int t0 = 0; t0 < TT; t0 += 8) {
    const int cur = (t0 >> 3) & 1;
    int tn = t0 + 8; if (tn >= TT) tn = 0;   // dead wrap prefetch
    load8(cur ^ 1, tn);
#pragma unroll
    for (int u = 0; u < 8; ++u) {
      s = fmaf(wv[cur][u], s, vv[cur][u] * kk[cur][u]);
      v_so[base + (long)(t0 + u) * DD] = __float2bfloat16(rv[cur][u] * s);
    }
  }
}

// ---- in-place RMSNorm over rows of 1024 (fp32 math, fp32 eps) ----
__global__ __launch_bounds__(256)
void rmsnorm_inplace(bf16* so)
{
  const long row = blockIdx.x;
  bf16* p = so + row * DD + threadIdx.x * 4;
  ushort4 u = *reinterpret_cast<const ushort4*>(p);
  float x0 = __uint_as_float((unsigned)u.x << 16);
  float x1 = __uint_as_float((unsigned)u.y << 16);
  float x2 = __uint_as_float((unsigned)u.z << 16);
  float x3 = __uint_as_float((unsigned)u.w << 16);
  float ss = x0*x0 + x1*x1 + x2*x2 + x3*x3;
#pragma unroll
  for (int m = 1; m <= 32; m <<= 1) ss += __shfl_xor(ss, m);
  __shared__ float part[4];
  if ((threadIdx.x & 63) == 0) part[threadIdx.x >> 6] = ss;
  __syncthreads();
  const float total = part[0] + part[1] + part[2] + part[3];
  const float scale = rsqrtf(total * (1.0f / DD) + 1.1920929e-07f);
  ushort4 pk;
  pk.x = f2bfbits(x0 * scale); pk.y = f2bfbits(x1 * scale);
  pk.z = f2bfbits(x2 * scale); pk.w = f2bfbits(x3 * scale);
  *reinterpret_cast<ushort4*>(p) = pk;
}

// ---- out = normed @ Wo^T, FP32 STORES to d_out ----
__global__ __launch_bounds__(256, 2)
void out_gemm_kernel(const bf16* __restrict__ A, const bf16* __restrict__ Wo_c,
                     float* __restrict__ out)
{
  __shared__ __align__(16) bf16 a_sh[128*32];
  __shared__ __align__(16) bf16 b_sh[128*32];
  f32x4 acc[4][4] = {};
  gemm_mainloop(A, Wo_c, blockIdx.y, blockIdx.x, a_sh, b_sh, acc);

  const int tid = threadIdx.x;
  const int wave = tid >> 6, lane = tid & 63;
  const int lane15 = lane & 15, quad = lane >> 4;
  const int waveM = wave >> 1, waveN = wave & 1;
  const int m_base = blockIdx.y * 128 + waveM * 64;
  const int n_base = blockIdx.x * 128 + waveN * 64;
#pragma unroll
  for (int mi = 0; mi < 4; ++mi)
#pragma unroll
    for (int ni = 0; ni < 4; ++ni)
#pragma unroll
      for (int r = 0; r < 4; ++r) {
        int m = m_base + mi*16 + quad*4 + r;
        int n = n_base + ni*16 + lane15;
        out[(long)m * DD + n] = acc[mi][ni][r];   // fp32 output
      }
}

extern "C" void kernel_launch(void* const* d_in, const int* in_sizes, int n_in,
                              void* d_out, int out_size, void* d_ws, size_t ws_size,
                              hipStream_t stream) {
  const float* x  = (const float*)d_in[0];
  const float* Wr = (const float*)d_in[1];
  const float* Wk = (const float*)d_in[2];
  const float* Wv = (const float*)d_in[3];
  const float* Ww = (const float*)d_in[4];
  const float* Wo = (const float*)d_in[5];

  const long NELT = (long)BB * TT * DD;            // 8388608
  bf16*  x_c  = (bf16*)d_ws;                       // 16 MiB
  bf16*  W_c  = x_c + NELT;                        // 8 MiB (Wr,Wv,Ww,Wo bf16)
  bf16*  v_so = W_c + 4 * 1048576;                 // 16 MiB (v -> scan-out -> normed)
  float* ksum = (float*)(v_so + NELT);             // 512 KiB
  float* wks  = ksum + (long)BB * NHH * TT;        // 64 KiB  (total ~40.6 MiB)

  // d_out scratch (fp32 buffer, 32 MiB): r bf16 [0,16M), w bf16 [16M,32M).
  bf16*  r_buf = (bf16*)d_out;
  bf16*  w_buf = (bf16*)d_out + NELT;
  float* out   = (float*)d_out;

  convert_kernel<<<dim3(12288), 256, 0, stream>>>(x, Wr, Wv, Ww, Wo, x_c, W_c);
  wksum_kernel<<<dim3(64), 256, 0, stream>>>(Wk, wks);
  proj_kernel<<<dim3(8, 64, 3), 256, 0, stream>>>(x_c, W_c, r_buf, v_so, w_buf);
  ksum_kernel<<<dim3(BB * TT), 256, 0, stream>>>(x_c, wks, ksum);
  scan_kernel<<<dim3(64), dim3(64), 0, stream>>>(r_buf, v_so, w_buf, ksum);
  rmsnorm_inplace<<<dim3(BB * TT), 256, 0, stream>>>(v_so);
  out_gemm_kernel<<<dim3(8, 64), 256, 0, stream>>>(v_so, W_c + 3 * 1048576, out);
}

// Round 8
// 270.505 us; speedup vs baseline: 6.5581x; 6.5581x over previous
//
#include <hip/hip_runtime.h>
#include <hip/hip_bf16.h>
#include <stdint.h>

// RWKV7-like block: B=4 T=2048 D=1024 NH=16 HD=64.
// Inputs fp32 (order x,Wr,Wk,Wv,Ww,Wo); OUTPUT FP32. Verified R7 (absmax .0195).
//
// Algebra: out_t[i] = r[i]*S[i], S[i] <- w[i]*S[i] + v[i]*Ksum,
//   Ksum[b,h,t] = x_t . (sum_j Wk[h*64+j,:]).
// R8: time-parallel scan. s_t = w_t*s_{t-1} + u_t is linear -> chunk it:
//   A-phase: per (channel, chunk of 32): P = prod w, A = local scan from 0
//   B-phase: per channel: carry composition over 64 chunks (writes chunk inits)
//   C-phase: re-scan chunk from init, out = r*s.  Depth 2048 -> 32+64+32.
//
// ws (~42.6 MiB): x_c bf16 16M | W_c bf16 8M | v_so bf16 16M | ksum 512K |
//   wks 64K | Pbuf 1M | Abuf 1M.  d_out scratch: r bf16 [0,16M), w bf16 [16M,32M).

#define BB 4
#define TT 2048
#define DD 1024
#define NHH 16
#define HDD 64
#define CC 64   // time chunks
#define LL 32   // chunk length
#define NCH 4096  // B*NH*HD channels

using bf16 = __hip_bfloat16;
typedef __attribute__((ext_vector_type(8))) short bfrag8;
typedef __attribute__((ext_vector_type(4))) float f32x4;

__device__ __forceinline__ void async_ld16(const bf16* g, bf16* l) {
  __builtin_amdgcn_global_load_lds(
      (const __attribute__((address_space(1))) uint32_t*)g,
      (__attribute__((address_space(3))) uint32_t*)l, 16, 0, 0);
}

__device__ __forceinline__ float sigm(float x) { return 1.0f / (1.0f + expf(-x)); }
__device__ __forceinline__ float bf2f(bf16 h) {
  unsigned short u = *reinterpret_cast<unsigned short*>(&h);
  return __uint_as_float((unsigned)u << 16);
}
__device__ __forceinline__ unsigned short f2bfbits(float f) {
  bf16 b = __float2bfloat16(f);
  return *reinterpret_cast<unsigned short*>(&b);
}

// ---- fp32 -> bf16: x (2097152 float4 groups) + Wr,Wv,Ww,Wo ----
__global__ __launch_bounds__(256)
void convert_kernel(const float* __restrict__ x,
                    const float* __restrict__ Wr, const float* __restrict__ Wv,
                    const float* __restrict__ Ww, const float* __restrict__ Wo,
                    bf16* __restrict__ x_c, bf16* __restrict__ W_c)
{
  const long g = (long)blockIdx.x * 256 + threadIdx.x;
  const float* src; bf16* dst; long off4;
  if (g < 2097152) { src = x; dst = x_c; off4 = g; }
  else {
    long gg = g - 2097152;
    int wsel = (int)(gg >> 18);
    off4 = gg & 262143;
    src = (wsel == 0) ? Wr : (wsel == 1) ? Wv : (wsel == 2) ? Ww : Wo;
    dst = W_c + (long)wsel * 1048576;
  }
  float4 f = reinterpret_cast<const float4*>(src)[off4];
  ushort4 pk;
  pk.x = f2bfbits(f.x); pk.y = f2bfbits(f.y);
  pk.z = f2bfbits(f.z); pk.w = f2bfbits(f.w);
  reinterpret_cast<ushort4*>(dst)[off4] = pk;
}

// ---- wks[h][c] = sum_{j<64} Wk[h*64+j][c] ----
__global__ __launch_bounds__(256)
void wksum_kernel(const float* __restrict__ Wk, float* __restrict__ wks)
{
  const int gid = blockIdx.x * 256 + threadIdx.x;
  const int h = gid >> 10, c = gid & 1023;
  float s = 0.0f;
  for (int j = 0; j < 64; ++j)
    s += Wk[(long)((h << 6) + j) * 1024 + c];
  wks[gid] = s;
}

// ---- MFMA GEMM mainloop (verified R7) ----
__device__ __forceinline__ void gemm_mainloop(
    const bf16* __restrict__ A, const bf16* __restrict__ W,
    int blockM, int blockN, bf16* a_sh, bf16* b_sh, f32x4 acc[4][4])
{
  const int tid    = threadIdx.x;
  const int wave   = tid >> 6;
  const int lane   = tid & 63;
  const int lane15 = lane & 15;
  const int quad   = lane >> 4;
  const int waveM  = wave >> 1;
  const int waveN  = wave & 1;
  const int s_row  = (wave << 5) + (lane >> 2);
  const int s_col  = (lane & 3) << 3;

  const bf16* gA = A + ((long)(blockM * 128) + s_row) * 1024 + s_col;
  const bf16* gW = W + ((long)(blockN * 128) + s_row) * 1024 + s_col;
  bf16* la = a_sh + wave * 1024;
  bf16* lb = b_sh + wave * 1024;

  for (int k0 = 0; k0 < 1024; k0 += 32) {
    async_ld16(gA + k0,            la);
    async_ld16(gA + k0 + 16*1024,  la + 512);
    async_ld16(gW + k0,            lb);
    async_ld16(gW + k0 + 16*1024,  lb + 512);
    __syncthreads();
    bfrag8 af[4], bfv[4];
#pragma unroll
    for (int mi = 0; mi < 4; ++mi)
      af[mi] = *reinterpret_cast<const bfrag8*>(a_sh + (waveM*64 + mi*16 + lane15)*32 + quad*8);
#pragma unroll
    for (int ni = 0; ni < 4; ++ni)
      bfv[ni] = *reinterpret_cast<const bfrag8*>(b_sh + (waveN*64 + ni*16 + lane15)*32 + quad*8);
#pragma unroll
    for (int mi = 0; mi < 4; ++mi)
#pragma unroll
      for (int ni = 0; ni < 4; ++ni)
        acc[mi][ni] = __builtin_amdgcn_mfma_f32_16x16x32_bf16(af[mi], bfv[ni], acc[mi][ni], 0, 0, 0);
    __syncthreads();
  }
}

// mode 0: r = sigm(x Wr^T)   1: v = x Wv^T   2: w = sigm(x Ww^T)*0.99
__global__ __launch_bounds__(256, 2)
void proj_kernel(const bf16* __restrict__ X, const bf16* __restrict__ W_c,
                 bf16* __restrict__ r_out, bf16* __restrict__ v_out,
                 bf16* __restrict__ w_out)
{
  __shared__ __align__(16) bf16 a_sh[128*32];
  __shared__ __align__(16) bf16 b_sh[128*32];
  const int mode = blockIdx.z;
  const bf16* W = W_c + (long)mode * 1048576;
  f32x4 acc[4][4] = {};
  gemm_mainloop(X, W, blockIdx.y, blockIdx.x, a_sh, b_sh, acc);

  const int tid = threadIdx.x;
  const int wave = tid >> 6, lane = tid & 63;
  const int lane15 = lane & 15, quad = lane >> 4;
  const int waveM = wave >> 1, waveN = wave & 1;
  const int m_base = blockIdx.y * 128 + waveM * 64;
  const int n_base = blockIdx.x * 128 + waveN * 64;
  bf16* outp = (mode == 0) ? r_out : (mode == 1) ? v_out : w_out;
#pragma unroll
  for (int mi = 0; mi < 4; ++mi)
#pragma unroll
    for (int ni = 0; ni < 4; ++ni)
#pragma unroll
      for (int r = 0; r < 4; ++r) {
        float val = acc[mi][ni][r];
        if (mode == 0) val = sigm(val);
        else if (mode == 2) val = sigm(val) * 0.99f;
        int m = m_base + mi*16 + quad*4 + r;
        int n = n_base + ni*16 + lane15;
        outp[(long)m * DD + n] = __float2bfloat16(val);
      }
}

// ---- ksum[b,h,t] = x_row(m) . wks[h] ----
__global__ __launch_bounds__(256)
void ksum_kernel(const bf16* __restrict__ X, const float* __restrict__ wks,
                 float* __restrict__ ksum)
{
  __shared__ __align__(8) bf16 xs[DD];
  const int m = blockIdx.x;
  const int tid = threadIdx.x;
  *reinterpret_cast<ushort4*>(xs + tid*4) =
      *reinterpret_cast<const ushort4*>(X + (long)m * DD + tid*4);
  __syncthreads();
  const int wave = tid >> 6, lane = tid & 63;
  const int b = m >> 11, t = m & (TT - 1);
#pragma unroll
  for (int hi = 0; hi < 4; ++hi) {
    const int h = wave * 4 + hi;
    float acc = 0.0f;
#pragma unroll
    for (int i = 0; i < 16; ++i) {
      const int c = lane + (i << 6);
      acc += bf2f(xs[c]) * wks[h * DD + c];
    }
#pragma unroll
    for (int msk = 1; msk <= 32; msk <<= 1) acc += __shfl_xor(acc, msk);
    if (lane == 0) ksum[((long)(b * NHH + h)) * TT + t] = acc;
  }
}

// ---- scan phase A: per (channel, chunk): P = prod w, A = local scan from 0 ----
// block 256 = 64 channels x 4 chunks; grid (64 bh, 16 chunk-groups)
__global__ __launch_bounds__(256)
void scanA_kernel(const bf16* __restrict__ v_buf, const bf16* __restrict__ w_buf,
                  const float* __restrict__ ksum,
                  float* __restrict__ Pbuf, float* __restrict__ Abuf)
{
  __shared__ float ks_sh[128];
  const int bh = blockIdx.x;
  const int b = bh >> 4, h = bh & 15;
  const int tid = threadIdx.x;
  const int i = tid & 63;
  const int cg = tid >> 6;                    // chunk within group
  const int chunk = blockIdx.y * 4 + cg;
  if (tid < 128) ks_sh[tid] = ksum[(long)bh * TT + blockIdx.y * 128 + tid];
  __syncthreads();
  const long base = (long)b * TT * DD + (long)(chunk * LL) * DD + h * HDD + i;
  float s = 0.0f, P = 1.0f;
#pragma unroll
  for (int j = 0; j < LL; ++j) {
    const long idx = base + (long)j * DD;
    float wv = bf2f(w_buf[idx]);
    float vv = bf2f(v_buf[idx]);
    s = fmaf(wv, s, vv * ks_sh[cg * LL + j]);
    P *= wv;
  }
  const int ch = bh * 64 + i;
  Pbuf[chunk * NCH + ch] = P;
  Abuf[chunk * NCH + ch] = s;
}

// ---- scan phase B: per channel, carry composition; Abuf[c] <- init of chunk c ----
__global__ __launch_bounds__(256)
void scanB_kernel(const float* __restrict__ Pbuf, float* __restrict__ Abuf)
{
  const int ch = blockIdx.x * 256 + threadIdx.x;   // 4096
  float carry = 0.0f;
  for (int c = 0; c < CC; ++c) {
    const int idx = c * NCH + ch;
    float p = Pbuf[idx];
    float a = Abuf[idx];
    Abuf[idx] = carry;
    carry = fmaf(p, carry, a);
  }
}

// ---- scan phase C: re-scan chunk from init, out = r*s (in-place on v_so) ----
__global__ __launch_bounds__(256)
void scanC_kernel(const bf16* __restrict__ r_buf, bf16* v_so,
                  const bf16* __restrict__ w_buf, const float* __restrict__ ksum,
                  const float* __restrict__ Abuf)
{
  __shared__ float ks_sh[128];
  const int bh = blockIdx.x;
  const int b = bh >> 4, h = bh & 15;
  const int tid = threadIdx.x;
  const int i = tid & 63;
  const int cg = tid >> 6;
  const int chunk = blockIdx.y * 4 + cg;
  if (tid < 128) ks_sh[tid] = ksum[(long)bh * TT + blockIdx.y * 128 + tid];
  __syncthreads();
  const int ch = bh * 64 + i;
  const long base = (long)b * TT * DD + (long)(chunk * LL) * DD + h * HDD + i;
  float s = Abuf[chunk * NCH + ch];
#pragma unroll
  for (int j = 0; j < LL; ++j) {
    const long idx = base + (long)j * DD;
    float wv = bf2f(w_buf[idx]);
    float vv = bf2f(v_so[idx]);
    float rv = bf2f(r_buf[idx]);
    s = fmaf(wv, s, vv * ks_sh[cg * LL + j]);
    v_so[idx] = __float2bfloat16(rv * s);
  }
}

// ---- in-place RMSNorm ----
__global__ __launch_bounds__(256)
void rmsnorm_inplace(bf16* so)
{
  const long row = blockIdx.x;
  bf16* p = so + row * DD + threadIdx.x * 4;
  ushort4 u = *reinterpret_cast<const ushort4*>(p);
  float x0 = __uint_as_float((unsigned)u.x << 16);
  float x1 = __uint_as_float((unsigned)u.y << 16);
  float x2 = __uint_as_float((unsigned)u.z << 16);
  float x3 = __uint_as_float((unsigned)u.w << 16);
  float ss = x0*x0 + x1*x1 + x2*x2 + x3*x3;
#pragma unroll
  for (int m = 1; m <= 32; m <<= 1) ss += __shfl_xor(ss, m);
  __shared__ float part[4];
  if ((threadIdx.x & 63) == 0) part[threadIdx.x >> 6] = ss;
  __syncthreads();
  const float total = part[0] + part[1] + part[2] + part[3];
  const float scale = rsqrtf(total * (1.0f / DD) + 1.1920929e-07f);
  ushort4 pk;
  pk.x = f2bfbits(x0 * scale); pk.y = f2bfbits(x1 * scale);
  pk.z = f2bfbits(x2 * scale); pk.w = f2bfbits(x3 * scale);
  *reinterpret_cast<ushort4*>(p) = pk;
}

// ---- out = normed @ Wo^T, fp32 stores ----
__global__ __launch_bounds__(256, 2)
void out_gemm_kernel(const bf16* __restrict__ A, const bf16* __restrict__ Wo_c,
                     float* __restrict__ out)
{
  __shared__ __align__(16) bf16 a_sh[128*32];
  __shared__ __align__(16) bf16 b_sh[128*32];
  f32x4 acc[4][4] = {};
  gemm_mainloop(A, Wo_c, blockIdx.y, blockIdx.x, a_sh, b_sh, acc);

  const int tid = threadIdx.x;
  const int wave = tid >> 6, lane = tid & 63;
  const int lane15 = lane & 15, quad = lane >> 4;
  const int waveM = wave >> 1, waveN = wave & 1;
  const int m_base = blockIdx.y * 128 + waveM * 64;
  const int n_base = blockIdx.x * 128 + waveN * 64;
#pragma unroll
  for (int mi = 0; mi < 4; ++mi)
#pragma unroll
    for (int ni = 0; ni < 4; ++ni)
#pragma unroll
      for (int r = 0; r < 4; ++r) {
        int m = m_base + mi*16 + quad*4 + r;
        int n = n_base + ni*16 + lane15;
        out[(long)m * DD + n] = acc[mi][ni][r];
      }
}

extern "C" void kernel_launch(void* const* d_in, const int* in_sizes, int n_in,
                              void* d_out, int out_size, void* d_ws, size_t ws_size,
                              hipStream_t stream) {
  const float* x  = (const float*)d_in[0];
  const float* Wr = (const float*)d_in[1];
  const float* Wk = (const float*)d_in[2];
  const float* Wv = (const float*)d_in[3];
  const float* Ww = (const float*)d_in[4];
  const float* Wo = (const float*)d_in[5];

  const long NELT = (long)BB * TT * DD;            // 8388608
  bf16*  x_c  = (bf16*)d_ws;                       // 16 MiB
  bf16*  W_c  = x_c + NELT;                        // 8 MiB
  bf16*  v_so = W_c + 4 * 1048576;                 // 16 MiB
  float* ksum = (float*)(v_so + NELT);             // 512 KiB
  float* wks  = ksum + (long)BB * NHH * TT;        // 64 KiB
  float* Pbuf = wks + NHH * DD;                    // 1 MiB
  float* Abuf = Pbuf + (long)CC * NCH;             // 1 MiB  (total ~42.6 MiB)

  bf16*  r_buf = (bf16*)d_out;                     // d_out scratch
  bf16*  w_buf = (bf16*)d_out + NELT;
  float* out   = (float*)d_out;

  convert_kernel<<<dim3(12288), 256, 0, stream>>>(x, Wr, Wv, Ww, Wo, x_c, W_c);
  wksum_kernel<<<dim3(64), 256, 0, stream>>>(Wk, wks);
  proj_kernel<<<dim3(8, 64, 3), 256, 0, stream>>>(x_c, W_c, r_buf, v_so, w_buf);
  ksum_kernel<<<dim3(BB * TT), 256, 0, stream>>>(x_c, wks, ksum);
  scanA_kernel<<<dim3(64, 16), 256, 0, stream>>>(v_so, w_buf, ksum, Pbuf, Abuf);
  scanB_kernel<<<dim3(16), 256, 0, stream>>>(Pbuf, Abuf);
  scanC_kernel<<<dim3(64, 16), 256, 0, stream>>>(r_buf, v_so, w_buf, ksum, Abuf);
  rmsnorm_inplace<<<dim3(BB * TT), 256, 0, stream>>>(v_so);
  out_gemm_kernel<<<dim3(8, 64), 256, 0, stream>>>(v_so, W_c + 3 * 1048576, out);
}

// Round 9
// 266.024 us; speedup vs baseline: 6.6685x; 1.0168x over previous
//
#include <hip/hip_runtime.h>
#include <hip/hip_bf16.h>
#include <stdint.h>

// RWKV7-like block: B=4 T=2048 D=1024 NH=16 HD=64.
// Inputs fp32 (order x,Wr,Wk,Wv,Ww,Wo); OUTPUT FP32. Verified R7/R8 (absmax .0195).
//
// R9: GEMM micro-opt, math unchanged:
//  (a) XOR-swizzled LDS tile (stage chunk (lane&3)^((lane>>2)&3), read chunk
//      quad^(row&3)) -> conflict-free ds_read_b128 (was ~8-way, 6.3M conflicts).
//  (b) XCD-pinned 1-D block swizzle: f = m%8 + 8*(n + 8*(mh + 8*z)), z-outer,
//      so an x M-tile's consumers share one XCD's L2 (fetch 148->~96 MB) and
//      weight slice stays resident across the mh sweep.
//
// ws (~42.6 MiB): x_c bf16 16M | W_c bf16 8M | v_so bf16 16M | ksum 512K |
//   wks 64K | Pbuf 1M | Abuf 1M.  d_out scratch: r bf16 [0,16M), w bf16 [16M,32M).

#define BB 4
#define TT 2048
#define DD 1024
#define NHH 16
#define HDD 64
#define CC 64
#define LL 32
#define NCH 4096

using bf16 = __hip_bfloat16;
typedef __attribute__((ext_vector_type(8))) short bfrag8;
typedef __attribute__((ext_vector_type(4))) float f32x4;

__device__ __forceinline__ void async_ld16(const bf16* g, bf16* l) {
  __builtin_amdgcn_global_load_lds(
      (const __attribute__((address_space(1))) uint32_t*)g,
      (__attribute__((address_space(3))) uint32_t*)l, 16, 0, 0);
}

__device__ __forceinline__ float sigm(float x) { return 1.0f / (1.0f + expf(-x)); }
__device__ __forceinline__ float bf2f(bf16 h) {
  unsigned short u = *reinterpret_cast<unsigned short*>(&h);
  return __uint_as_float((unsigned)u << 16);
}
__device__ __forceinline__ unsigned short f2bfbits(float f) {
  bf16 b = __float2bfloat16(f);
  return *reinterpret_cast<unsigned short*>(&b);
}

// ---- fp32 -> bf16: x (2097152 float4 groups) + Wr,Wv,Ww,Wo ----
__global__ __launch_bounds__(256)
void convert_kernel(const float* __restrict__ x,
                    const float* __restrict__ Wr, const float* __restrict__ Wv,
                    const float* __restrict__ Ww, const float* __restrict__ Wo,
                    bf16* __restrict__ x_c, bf16* __restrict__ W_c)
{
  const long g = (long)blockIdx.x * 256 + threadIdx.x;
  const float* src; bf16* dst; long off4;
  if (g < 2097152) { src = x; dst = x_c; off4 = g; }
  else {
    long gg = g - 2097152;
    int wsel = (int)(gg >> 18);
    off4 = gg & 262143;
    src = (wsel == 0) ? Wr : (wsel == 1) ? Wv : (wsel == 2) ? Ww : Wo;
    dst = W_c + (long)wsel * 1048576;
  }
  float4 f = reinterpret_cast<const float4*>(src)[off4];
  ushort4 pk;
  pk.x = f2bfbits(f.x); pk.y = f2bfbits(f.y);
  pk.z = f2bfbits(f.z); pk.w = f2bfbits(f.w);
  reinterpret_cast<ushort4*>(dst)[off4] = pk;
}

// ---- wks[h][c] = sum_{j<64} Wk[h*64+j][c] ----
__global__ __launch_bounds__(256)
void wksum_kernel(const float* __restrict__ Wk, float* __restrict__ wks)
{
  const int gid = blockIdx.x * 256 + threadIdx.x;
  const int h = gid >> 10, c = gid & 1023;
  float s = 0.0f;
  for (int j = 0; j < 64; ++j)
    s += Wk[(long)((h << 6) + j) * 1024 + c];
  wks[gid] = s;
}

// ---- MFMA GEMM mainloop, XOR-swizzled LDS (conflict-free b128 reads) ----
// LDS[row][phys16B] = global[row][phys ^ (row&3)]; read chunk quad^(row&3).
__device__ __forceinline__ void gemm_mainloop(
    const bf16* __restrict__ A, const bf16* __restrict__ W,
    int blockM, int blockN, bf16* a_sh, bf16* b_sh, f32x4 acc[4][4])
{
  const int tid    = threadIdx.x;
  const int wave   = tid >> 6;
  const int lane   = tid & 63;
  const int lane15 = lane & 15;
  const int quad   = lane >> 4;
  const int waveM  = wave >> 1;
  const int waveN  = wave & 1;
  const int s_row  = (wave << 5) + (lane >> 2);
  const int s_col  = (((lane & 3) ^ ((lane >> 2) & 3)) << 3);   // swizzled chunk

  const bf16* gA = A + ((long)(blockM * 128) + s_row) * 1024 + s_col;
  const bf16* gW = W + ((long)(blockN * 128) + s_row) * 1024 + s_col;
  bf16* la = a_sh + wave * 1024;   // wave-uniform base; HW scatters +lane*16B
  bf16* lb = b_sh + wave * 1024;

  const int sw = (quad ^ (lane15 & 3)) << 3;                    // read-side chunk

  for (int k0 = 0; k0 < 1024; k0 += 32) {
    async_ld16(gA + k0,            la);
    async_ld16(gA + k0 + 16*1024,  la + 512);
    async_ld16(gW + k0,            lb);
    async_ld16(gW + k0 + 16*1024,  lb + 512);
    __syncthreads();
    bfrag8 af[4], bfv[4];
#pragma unroll
    for (int mi = 0; mi < 4; ++mi)
      af[mi] = *reinterpret_cast<const bfrag8*>(a_sh + (waveM*64 + mi*16 + lane15)*32 + sw);
#pragma unroll
    for (int ni = 0; ni < 4; ++ni)
      bfv[ni] = *reinterpret_cast<const bfrag8*>(b_sh + (waveN*64 + ni*16 + lane15)*32 + sw);
#pragma unroll
    for (int mi = 0; mi < 4; ++mi)
#pragma unroll
      for (int ni = 0; ni < 4; ++ni)
        acc[mi][ni] = __builtin_amdgcn_mfma_f32_16x16x32_bf16(af[mi], bfv[ni], acc[mi][ni], 0, 0, 0);
    __syncthreads();
  }
}

// mode 0: r = sigm(x Wr^T)   1: v = x Wv^T   2: w = sigm(x Ww^T)*0.99
// 1-D grid 1536, XCD-pinned: f = m%8 + 8*(n + 8*(mh + 8*z)), m = m%8 + 8*mh.
__global__ __launch_bounds__(256, 2)
void proj_kernel(const bf16* __restrict__ X, const bf16* __restrict__ W_c,
                 bf16* __restrict__ r_out, bf16* __restrict__ v_out,
                 bf16* __restrict__ w_out)
{
  __shared__ __align__(16) bf16 a_sh[128*32];
  __shared__ __align__(16) bf16 b_sh[128*32];
  const int f  = blockIdx.x;
  const int u  = f & 7;
  const int q  = f >> 3;
  const int n  = q & 7;
  const int p  = q >> 3;        // [0,24)
  const int mh = p & 7;
  const int mode = p >> 3;      // [0,3)
  const int m  = u + (mh << 3); // [0,64)

  const bf16* W = W_c + (long)mode * 1048576;
  f32x4 acc[4][4] = {};
  gemm_mainloop(X, W, m, n, a_sh, b_sh, acc);

  const int tid = threadIdx.x;
  const int wave = tid >> 6, lane = tid & 63;
  const int lane15 = lane & 15, quad = lane >> 4;
  const int waveM = wave >> 1, waveN = wave & 1;
  const int m_base = m * 128 + waveM * 64;
  const int n_base = n * 128 + waveN * 64;
  bf16* outp = (mode == 0) ? r_out : (mode == 1) ? v_out : w_out;
#pragma unroll
  for (int mi = 0; mi < 4; ++mi)
#pragma unroll
    for (int ni = 0; ni < 4; ++ni)
#pragma unroll
      for (int r = 0; r < 4; ++r) {
        float val = acc[mi][ni][r];
        if (mode == 0) val = sigm(val);
        else if (mode == 2) val = sigm(val) * 0.99f;
        int mm = m_base + mi*16 + quad*4 + r;
        int nn = n_base + ni*16 + lane15;
        outp[(long)mm * DD + nn] = __float2bfloat16(val);
      }
}

// ---- ksum[b,h,t] = x_row(m) . wks[h] ----
__global__ __launch_bounds__(256)
void ksum_kernel(const bf16* __restrict__ X, const float* __restrict__ wks,
                 float* __restrict__ ksum)
{
  __shared__ __align__(8) bf16 xs[DD];
  const int m = blockIdx.x;
  const int tid = threadIdx.x;
  *reinterpret_cast<ushort4*>(xs + tid*4) =
      *reinterpret_cast<const ushort4*>(X + (long)m * DD + tid*4);
  __syncthreads();
  const int wave = tid >> 6, lane = tid & 63;
  const int b = m >> 11, t = m & (TT - 1);
#pragma unroll
  for (int hi = 0; hi < 4; ++hi) {
    const int h = wave * 4 + hi;
    float acc = 0.0f;
#pragma unroll
    for (int i = 0; i < 16; ++i) {
      const int c = lane + (i << 6);
      acc += bf2f(xs[c]) * wks[h * DD + c];
    }
#pragma unroll
    for (int msk = 1; msk <= 32; msk <<= 1) acc += __shfl_xor(acc, msk);
    if (lane == 0) ksum[((long)(b * NHH + h)) * TT + t] = acc;
  }
}

// ---- scan A: per (channel, chunk): P = prod w, A = local scan from 0 ----
__global__ __launch_bounds__(256)
void scanA_kernel(const bf16* __restrict__ v_buf, const bf16* __restrict__ w_buf,
                  const float* __restrict__ ksum,
                  float* __restrict__ Pbuf, float* __restrict__ Abuf)
{
  __shared__ float ks_sh[128];
  const int bh = blockIdx.x;
  const int b = bh >> 4, h = bh & 15;
  const int tid = threadIdx.x;
  const int i = tid & 63;
  const int cg = tid >> 6;
  const int chunk = blockIdx.y * 4 + cg;
  if (tid < 128) ks_sh[tid] = ksum[(long)bh * TT + blockIdx.y * 128 + tid];
  __syncthreads();
  const long base = (long)b * TT * DD + (long)(chunk * LL) * DD + h * HDD + i;
  float s = 0.0f, P = 1.0f;
#pragma unroll
  for (int j = 0; j < LL; ++j) {
    const long idx = base + (long)j * DD;
    float wv = bf2f(w_buf[idx]);
    float vv = bf2f(v_buf[idx]);
    s = fmaf(wv, s, vv * ks_sh[cg * LL + j]);
    P *= wv;
  }
  const int ch = bh * 64 + i;
  Pbuf[chunk * NCH + ch] = P;
  Abuf[chunk * NCH + ch] = s;
}

// ---- scan B: per channel carry composition; Abuf[c] <- chunk init ----
__global__ __launch_bounds__(256)
void scanB_kernel(const float* __restrict__ Pbuf, float* __restrict__ Abuf)
{
  const int ch = blockIdx.x * 256 + threadIdx.x;
  float carry = 0.0f;
  for (int c = 0; c < CC; ++c) {
    const int idx = c * NCH + ch;
    float p = Pbuf[idx];
    float a = Abuf[idx];
    Abuf[idx] = carry;
    carry = fmaf(p, carry, a);
  }
}

// ---- scan C: re-scan chunk from init, out = r*s (in-place on v_so) ----
__global__ __launch_bounds__(256)
void scanC_kernel(const bf16* __restrict__ r_buf, bf16* v_so,
                  const bf16* __restrict__ w_buf, const float* __restrict__ ksum,
                  const float* __restrict__ Abuf)
{
  __shared__ float ks_sh[128];
  const int bh = blockIdx.x;
  const int b = bh >> 4, h = bh & 15;
  const int tid = threadIdx.x;
  const int i = tid & 63;
  const int cg = tid >> 6;
  const int chunk = blockIdx.y * 4 + cg;
  if (tid < 128) ks_sh[tid] = ksum[(long)bh * TT + blockIdx.y * 128 + tid];
  __syncthreads();
  const int ch = bh * 64 + i;
  const long base = (long)b * TT * DD + (long)(chunk * LL) * DD + h * HDD + i;
  float s = Abuf[chunk * NCH + ch];
#pragma unroll
  for (int j = 0; j < LL; ++j) {
    const long idx = base + (long)j * DD;
    float wv = bf2f(w_buf[idx]);
    float vv = bf2f(v_so[idx]);
    float rv = bf2f(r_buf[idx]);
    s = fmaf(wv, s, vv * ks_sh[cg * LL + j]);
    v_so[idx] = __float2bfloat16(rv * s);
  }
}

// ---- in-place RMSNorm ----
__global__ __launch_bounds__(256)
void rmsnorm_inplace(bf16* so)
{
  const long row = blockIdx.x;
  bf16* p = so + row * DD + threadIdx.x * 4;
  ushort4 u = *reinterpret_cast<const ushort4*>(p);
  float x0 = __uint_as_float((unsigned)u.x << 16);
  float x1 = __uint_as_float((unsigned)u.y << 16);
  float x2 = __uint_as_float((unsigned)u.z << 16);
  float x3 = __uint_as_float((unsigned)u.w << 16);
  float ss = x0*x0 + x1*x1 + x2*x2 + x3*x3;
#pragma unroll
  for (int m = 1; m <= 32; m <<= 1) ss += __shfl_xor(ss, m);
  __shared__ float part[4];
  if ((threadIdx.x & 63) == 0) part[threadIdx.x >> 6] = ss;
  __syncthreads();
  const float total = part[0] + part[1] + part[2] + part[3];
  const float scale = rsqrtf(total * (1.0f / DD) + 1.1920929e-07f);
  ushort4 pk;
  pk.x = f2bfbits(x0 * scale); pk.y = f2bfbits(x1 * scale);
  pk.z = f2bfbits(x2 * scale); pk.w = f2bfbits(x3 * scale);
  *reinterpret_cast<ushort4*>(p) = pk;
}

// ---- out = normed @ Wo^T, fp32 stores. 1-D grid 512, XCD-pinned. ----
__global__ __launch_bounds__(256, 2)
void out_gemm_kernel(const bf16* __restrict__ A, const bf16* __restrict__ Wo_c,
                     float* __restrict__ out)
{
  __shared__ __align__(16) bf16 a_sh[128*32];
  __shared__ __align__(16) bf16 b_sh[128*32];
  const int f  = blockIdx.x;
  const int u  = f & 7;
  const int q  = f >> 3;
  const int n  = q & 7;
  const int mh = q >> 3;        // [0,8)
  const int m  = u + (mh << 3);

  f32x4 acc[4][4] = {};
  gemm_mainloop(A, Wo_c, m, n, a_sh, b_sh, acc);

  const int tid = threadIdx.x;
  const int wave = tid >> 6, lane = tid & 63;
  const int lane15 = lane & 15, quad = lane >> 4;
  const int waveM = wave >> 1, waveN = wave & 1;
  const int m_base = m * 128 + waveM * 64;
  const int n_base = n * 128 + waveN * 64;
#pragma unroll
  for (int mi = 0; mi < 4; ++mi)
#pragma unroll
    for (int ni = 0; ni < 4; ++ni)
#pragma unroll
      for (int r = 0; r < 4; ++r) {
        int mm = m_base + mi*16 + quad*4 + r;
        int nn = n_base + ni*16 + lane15;
        out[(long)mm * DD + nn] = acc[mi][ni][r];
      }
}

extern "C" void kernel_launch(void* const* d_in, const int* in_sizes, int n_in,
                              void* d_out, int out_size, void* d_ws, size_t ws_size,
                              hipStream_t stream) {
  const float* x  = (const float*)d_in[0];
  const float* Wr = (const float*)d_in[1];
  const float* Wk = (const float*)d_in[2];
  const float* Wv = (const float*)d_in[3];
  const float* Ww = (const float*)d_in[4];
  const float* Wo = (const float*)d_in[5];

  const long NELT = (long)BB * TT * DD;            // 8388608
  bf16*  x_c  = (bf16*)d_ws;                       // 16 MiB
  bf16*  W_c  = x_c + NELT;                        // 8 MiB
  bf16*  v_so = W_c + 4 * 1048576;                 // 16 MiB
  float* ksum = (float*)(v_so + NELT);             // 512 KiB
  float* wks  = ksum + (long)BB * NHH * TT;        // 64 KiB
  float* Pbuf = wks + NHH * DD;                    // 1 MiB
  float* Abuf = Pbuf + (long)CC * NCH;             // 1 MiB

  bf16*  r_buf = (bf16*)d_out;                     // d_out scratch
  bf16*  w_buf = (bf16*)d_out + NELT;
  float* out   = (float*)d_out;

  convert_kernel<<<dim3(12288), 256, 0, stream>>>(x, Wr, Wv, Ww, Wo, x_c, W_c);
  wksum_kernel<<<dim3(64), 256, 0, stream>>>(Wk, wks);
  proj_kernel<<<dim3(1536), 256, 0, stream>>>(x_c, W_c, r_buf, v_so, w_buf);
  ksum_kernel<<<dim3(BB * TT), 256, 0, stream>>>(x_c, wks, ksum);
  scanA_kernel<<<dim3(64, 16), 256, 0, stream>>>(v_so, w_buf, ksum, Pbuf, Abuf);
  scanB_kernel<<<dim3(16), 256, 0, stream>>>(Pbuf, Abuf);
  scanC_kernel<<<dim3(64, 16), 256, 0, stream>>>(r_buf, v_so, w_buf, ksum, Abuf);
  rmsnorm_inplace<<<dim3(BB * TT), 256, 0, stream>>>(v_so);
  out_gemm_kernel<<<dim3(512), 256, 0, stream>>>(v_so, W_c + 3 * 1048576, out);
}

// Round 10
// 228.670 us; speedup vs baseline: 7.7578x; 1.1634x over previous
//
#include <hip/hip_runtime.h>
#include <hip/hip_bf16.h>
#include <stdint.h>

// RWKV7-like block: B=4 T=2048 D=1024 NH=16 HD=64.
// Inputs fp32 (order x,Wr,Wk,Wv,Ww,Wo); OUTPUT FP32. Verified R7-R9 (absmax .0195).
//
// R10: BK=64 K-loop (barrier pairs 32->16, 32 MFMA/barrier) with XOR-chunk
// staging permutation (physical chunk p of row r holds global chunk p^(r&7);
// avoids the 16-way conflict of the 128B row stride while keeping the
// lane-contiguous LDS dest global_load_lds requires). Fast sigmoid in
// epilogue (v_exp+v_rcp, was libm expf). wksum fused into convert.
// NOTE (R9 post-mortem): SQ_LDS_BANK_CONFLICT ~ 4/ds_read_b128 is the
// structural wave64 b128 replay, not real conflicts - don't chase it.
//
// ws (~42.6 MiB): x_c bf16 16M | W_c bf16 8M | v_so bf16 16M | ksum 512K |
//   wks 64K | Pbuf 1M | Abuf 1M.  d_out scratch: r bf16 [0,16M), w bf16 [16M,32M).

#define BB 4
#define TT 2048
#define DD 1024
#define NHH 16
#define HDD 64
#define CC 64
#define LL 32
#define NCH 4096

using bf16 = __hip_bfloat16;
typedef __attribute__((ext_vector_type(8))) short bfrag8;
typedef __attribute__((ext_vector_type(4))) float f32x4;

__device__ __forceinline__ void async_ld16(const bf16* g, bf16* l) {
  __builtin_amdgcn_global_load_lds(
      (const __attribute__((address_space(1))) uint32_t*)g,
      (__attribute__((address_space(3))) uint32_t*)l, 16, 0, 0);
}

__device__ __forceinline__ float sigm(float x) {
  // fast: v_exp_f32 + v_rcp_f32 (~1 ulp each; bf16 rounding downstream dominates)
  return __builtin_amdgcn_rcpf(1.0f + __expf(-x));
}
__device__ __forceinline__ float bf2f(bf16 h) {
  unsigned short u = *reinterpret_cast<unsigned short*>(&h);
  return __uint_as_float((unsigned)u << 16);
}
__device__ __forceinline__ unsigned short f2bfbits(float f) {
  bf16 b = __float2bfloat16(f);
  return *reinterpret_cast<unsigned short*>(&b);
}

// ---- fp32 -> bf16 convert (x + Wr,Wv,Ww,Wo) fused with wksum ----
// blocks [0,12288): convert; blocks [12288,12352): wks[h][c]=sum_j Wk[h*64+j][c]
__global__ __launch_bounds__(256)
void convert_kernel(const float* __restrict__ x,
                    const float* __restrict__ Wr, const float* __restrict__ Wv,
                    const float* __restrict__ Ww, const float* __restrict__ Wo,
                    const float* __restrict__ Wk,
                    bf16* __restrict__ x_c, bf16* __restrict__ W_c,
                    float* __restrict__ wks)
{
  if (blockIdx.x >= 12288) {
    const int gid = (blockIdx.x - 12288) * 256 + threadIdx.x;   // 16384
    const int h = gid >> 10, c = gid & 1023;
    float s = 0.0f;
    for (int j = 0; j < 64; ++j)
      s += Wk[(long)((h << 6) + j) * 1024 + c];
    wks[gid] = s;
    return;
  }
  const long g = (long)blockIdx.x * 256 + threadIdx.x;
  const float* src; bf16* dst; long off4;
  if (g < 2097152) { src = x; dst = x_c; off4 = g; }
  else {
    long gg = g - 2097152;
    int wsel = (int)(gg >> 18);
    off4 = gg & 262143;
    src = (wsel == 0) ? Wr : (wsel == 1) ? Wv : (wsel == 2) ? Ww : Wo;
    dst = W_c + (long)wsel * 1048576;
  }
  float4 f = reinterpret_cast<const float4*>(src)[off4];
  ushort4 pk;
  pk.x = f2bfbits(f.x); pk.y = f2bfbits(f.y);
  pk.z = f2bfbits(f.z); pk.w = f2bfbits(f.w);
  reinterpret_cast<ushort4*>(dst)[off4] = pk;
}

// ---- MFMA GEMM mainloop, BK=64, XOR-chunk staging permutation ----
// LDS row-major [128][64] bf16 (8 chunks of 16B per row).
// Staging: lane l (of a wave issue) covers row (l>>3), phys chunk (l&7),
// fetching GLOBAL chunk (l&7)^((l>>3)&7). Reads fetch phys (kh*4+quad)^(lane15&7).
__device__ __forceinline__ void gemm_mainloop(
    const bf16* __restrict__ A, const bf16* __restrict__ W,
    int blockM, int blockN, bf16* a_sh, bf16* b_sh, f32x4 acc[4][4])
{
  const int tid    = threadIdx.x;
  const int wave   = tid >> 6;
  const int lane   = tid & 63;
  const int lane15 = lane & 15;
  const int quad   = lane >> 4;
  const int waveM  = wave >> 1;
  const int waveN  = wave & 1;
  const int s_row  = (wave << 5) + (lane >> 3);                 // +it*8 below
  const int s_col  = (((lane & 7) ^ ((lane >> 3) & 7)) << 3);   // permuted global chunk

  const bf16* gA = A + ((long)(blockM * 128) + s_row) * 1024 + s_col;
  const bf16* gW = W + ((long)(blockN * 128) + s_row) * 1024 + s_col;
  bf16* la = a_sh + wave * 2048;   // 32 rows x 64 elems per wave
  bf16* lb = b_sh + wave * 2048;

  const int rsw = lane15 & 7;      // read-side xor key (= local row & 7)

  for (int k0 = 0; k0 < 1024; k0 += 64) {
#pragma unroll
    for (int it = 0; it < 4; ++it) {
      async_ld16(gA + k0 + it * 8 * 1024, la + it * 512);
      async_ld16(gW + k0 + it * 8 * 1024, lb + it * 512);
    }
    __syncthreads();
#pragma unroll
    for (int kh = 0; kh < 2; ++kh) {
      bfrag8 af[4], bfv[4];
      const int pc = ((kh * 4 + quad) ^ rsw) << 3;   // phys chunk elem offset
#pragma unroll
      for (int mi = 0; mi < 4; ++mi)
        af[mi] = *reinterpret_cast<const bfrag8*>(a_sh + (waveM*64 + mi*16 + lane15)*64 + pc);
#pragma unroll
      for (int ni = 0; ni < 4; ++ni)
        bfv[ni] = *reinterpret_cast<const bfrag8*>(b_sh + (waveN*64 + ni*16 + lane15)*64 + pc);
#pragma unroll
      for (int mi = 0; mi < 4; ++mi)
#pragma unroll
        for (int ni = 0; ni < 4; ++ni)
          acc[mi][ni] = __builtin_amdgcn_mfma_f32_16x16x32_bf16(af[mi], bfv[ni], acc[mi][ni], 0, 0, 0);
    }
    __syncthreads();
  }
}

// mode 0: r = sigm(x Wr^T)   1: v = x Wv^T   2: w = sigm(x Ww^T)*0.99
// 1-D grid 1536, XCD-pinned: f = m%8 + 8*(n + 8*(mh + 8*mode)).
__global__ __launch_bounds__(256, 2)
void proj_kernel(const bf16* __restrict__ X, const bf16* __restrict__ W_c,
                 bf16* __restrict__ r_out, bf16* __restrict__ v_out,
                 bf16* __restrict__ w_out)
{
  __shared__ __align__(16) bf16 a_sh[128*64];
  __shared__ __align__(16) bf16 b_sh[128*64];
  const int f  = blockIdx.x;
  const int u  = f & 7;
  const int q  = f >> 3;
  const int n  = q & 7;
  const int p  = q >> 3;
  const int mh = p & 7;
  const int mode = p >> 3;
  const int m  = u + (mh << 3);

  const bf16* W = W_c + (long)mode * 1048576;
  f32x4 acc[4][4] = {};
  gemm_mainloop(X, W, m, n, a_sh, b_sh, acc);

  const int tid = threadIdx.x;
  const int wave = tid >> 6, lane = tid & 63;
  const int lane15 = lane & 15, quad = lane >> 4;
  const int waveM = wave >> 1, waveN = wave & 1;
  const int m_base = m * 128 + waveM * 64;
  const int n_base = n * 128 + waveN * 64;
  bf16* outp = (mode == 0) ? r_out : (mode == 1) ? v_out : w_out;
#pragma unroll
  for (int mi = 0; mi < 4; ++mi)
#pragma unroll
    for (int ni = 0; ni < 4; ++ni)
#pragma unroll
      for (int r = 0; r < 4; ++r) {
        float val = acc[mi][ni][r];
        if (mode == 0) val = sigm(val);
        else if (mode == 2) val = sigm(val) * 0.99f;
        int mm = m_base + mi*16 + quad*4 + r;
        int nn = n_base + ni*16 + lane15;
        outp[(long)mm * DD + nn] = __float2bfloat16(val);
      }
}

// ---- ksum[b,h,t] = x_row(m) . wks[h] ----
__global__ __launch_bounds__(256)
void ksum_kernel(const bf16* __restrict__ X, const float* __restrict__ wks,
                 float* __restrict__ ksum)
{
  __shared__ __align__(8) bf16 xs[DD];
  const int m = blockIdx.x;
  const int tid = threadIdx.x;
  *reinterpret_cast<ushort4*>(xs + tid*4) =
      *reinterpret_cast<const ushort4*>(X + (long)m * DD + tid*4);
  __syncthreads();
  const int wave = tid >> 6, lane = tid & 63;
  const int b = m >> 11, t = m & (TT - 1);
#pragma unroll
  for (int hi = 0; hi < 4; ++hi) {
    const int h = wave * 4 + hi;
    float acc = 0.0f;
#pragma unroll
    for (int i = 0; i < 16; ++i) {
      const int c = lane + (i << 6);
      acc += bf2f(xs[c]) * wks[h * DD + c];
    }
#pragma unroll
    for (int msk = 1; msk <= 32; msk <<= 1) acc += __shfl_xor(acc, msk);
    if (lane == 0) ksum[((long)(b * NHH + h)) * TT + t] = acc;
  }
}

// ---- scan A: per (channel, chunk): P = prod w, A = local scan from 0 ----
__global__ __launch_bounds__(256)
void scanA_kernel(const bf16* __restrict__ v_buf, const bf16* __restrict__ w_buf,
                  const float* __restrict__ ksum,
                  float* __restrict__ Pbuf, float* __restrict__ Abuf)
{
  __shared__ float ks_sh[128];
  const int bh = blockIdx.x;
  const int b = bh >> 4, h = bh & 15;
  const int tid = threadIdx.x;
  const int i = tid & 63;
  const int cg = tid >> 6;
  const int chunk = blockIdx.y * 4 + cg;
  if (tid < 128) ks_sh[tid] = ksum[(long)bh * TT + blockIdx.y * 128 + tid];
  __syncthreads();
  const long base = (long)b * TT * DD + (long)(chunk * LL) * DD + h * HDD + i;
  float s = 0.0f, P = 1.0f;
#pragma unroll
  for (int j = 0; j < LL; ++j) {
    const long idx = base + (long)j * DD;
    float wv = bf2f(w_buf[idx]);
    float vv = bf2f(v_buf[idx]);
    s = fmaf(wv, s, vv * ks_sh[cg * LL + j]);
    P *= wv;
  }
  const int ch = bh * 64 + i;
  Pbuf[chunk * NCH + ch] = P;
  Abuf[chunk * NCH + ch] = s;
}

// ---- scan B: per channel carry composition; Abuf[c] <- chunk init ----
__global__ __launch_bounds__(256)
void scanB_kernel(const float* __restrict__ Pbuf, float* __restrict__ Abuf)
{
  const int ch = blockIdx.x * 256 + threadIdx.x;
  float carry = 0.0f;
  for (int c = 0; c < CC; ++c) {
    const int idx = c * NCH + ch;
    float p = Pbuf[idx];
    float a = Abuf[idx];
    Abuf[idx] = carry;
    carry = fmaf(p, carry, a);
  }
}

// ---- scan C: re-scan chunk from init, out = r*s (in-place on v_so) ----
__global__ __launch_bounds__(256)
void scanC_kernel(const bf16* __restrict__ r_buf, bf16* v_so,
                  const bf16* __restrict__ w_buf, const float* __restrict__ ksum,
                  const float* __restrict__ Abuf)
{
  __shared__ float ks_sh[128];
  const int bh = blockIdx.x;
  const int b = bh >> 4, h = bh & 15;
  const int tid = threadIdx.x;
  const int i = tid & 63;
  const int cg = tid >> 6;
  const int chunk = blockIdx.y * 4 + cg;
  if (tid < 128) ks_sh[tid] = ksum[(long)bh * TT + blockIdx.y * 128 + tid];
  __syncthreads();
  const int ch = bh * 64 + i;
  const long base = (long)b * TT * DD + (long)(chunk * LL) * DD + h * HDD + i;
  float s = Abuf[chunk * NCH + ch];
#pragma unroll
  for (int j = 0; j < LL; ++j) {
    const long idx = base + (long)j * DD;
    float wv = bf2f(w_buf[idx]);
    float vv = bf2f(v_so[idx]);
    float rv = bf2f(r_buf[idx]);
    s = fmaf(wv, s, vv * ks_sh[cg * LL + j]);
    v_so[idx] = __float2bfloat16(rv * s);
  }
}

// ---- in-place RMSNorm ----
__global__ __launch_bounds__(256)
void rmsnorm_inplace(bf16* so)
{
  const long row = blockIdx.x;
  bf16* p = so + row * DD + threadIdx.x * 4;
  ushort4 u = *reinterpret_cast<const ushort4*>(p);
  float x0 = __uint_as_float((unsigned)u.x << 16);
  float x1 = __uint_as_float((unsigned)u.y << 16);
  float x2 = __uint_as_float((unsigned)u.z << 16);
  float x3 = __uint_as_float((unsigned)u.w << 16);
  float ss = x0*x0 + x1*x1 + x2*x2 + x3*x3;
#pragma unroll
  for (int m = 1; m <= 32; m <<= 1) ss += __shfl_xor(ss, m);
  __shared__ float part[4];
  if ((threadIdx.x & 63) == 0) part[threadIdx.x >> 6] = ss;
  __syncthreads();
  const float total = part[0] + part[1] + part[2] + part[3];
  const float scale = rsqrtf(total * (1.0f / DD) + 1.1920929e-07f);
  ushort4 pk;
  pk.x = f2bfbits(x0 * scale); pk.y = f2bfbits(x1 * scale);
  pk.z = f2bfbits(x2 * scale); pk.w = f2bfbits(x3 * scale);
  *reinterpret_cast<ushort4*>(p) = pk;
}

// ---- out = normed @ Wo^T, fp32 stores. 1-D grid 512, XCD-pinned. ----
__global__ __launch_bounds__(256, 2)
void out_gemm_kernel(const bf16* __restrict__ A, const bf16* __restrict__ Wo_c,
                     float* __restrict__ out)
{
  __shared__ __align__(16) bf16 a_sh[128*64];
  __shared__ __align__(16) bf16 b_sh[128*64];
  const int f  = blockIdx.x;
  const int u  = f & 7;
  const int q  = f >> 3;
  const int n  = q & 7;
  const int mh = q >> 3;
  const int m  = u + (mh << 3);

  f32x4 acc[4][4] = {};
  gemm_mainloop(A, Wo_c, m, n, a_sh, b_sh, acc);

  const int tid = threadIdx.x;
  const int wave = tid >> 6, lane = tid & 63;
  const int lane15 = lane & 15, quad = lane >> 4;
  const int waveM = wave >> 1, waveN = wave & 1;
  const int m_base = m * 128 + waveM * 64;
  const int n_base = n * 128 + waveN * 64;
#pragma unroll
  for (int mi = 0; mi < 4; ++mi)
#pragma unroll
    for (int ni = 0; ni < 4; ++ni)
#pragma unroll
      for (int r = 0; r < 4; ++r) {
        int mm = m_base + mi*16 + quad*4 + r;
        int nn = n_base + ni*16 + lane15;
        out[(long)mm * DD + nn] = acc[mi][ni][r];
      }
}

extern "C" void kernel_launch(void* const* d_in, const int* in_sizes, int n_in,
                              void* d_out, int out_size, void* d_ws, size_t ws_size,
                              hipStream_t stream) {
  const float* x  = (const float*)d_in[0];
  const float* Wr = (const float*)d_in[1];
  const float* Wk = (const float*)d_in[2];
  const float* Wv = (const float*)d_in[3];
  const float* Ww = (const float*)d_in[4];
  const float* Wo = (const float*)d_in[5];

  const long NELT = (long)BB * TT * DD;            // 8388608
  bf16*  x_c  = (bf16*)d_ws;                       // 16 MiB
  bf16*  W_c  = x_c + NELT;                        // 8 MiB
  bf16*  v_so = W_c + 4 * 1048576;                 // 16 MiB
  float* ksum = (float*)(v_so + NELT);             // 512 KiB
  float* wks  = ksum + (long)BB * NHH * TT;        // 64 KiB
  float* Pbuf = wks + NHH * DD;                    // 1 MiB
  float* Abuf = Pbuf + (long)CC * NCH;             // 1 MiB

  bf16*  r_buf = (bf16*)d_out;                     // d_out scratch
  bf16*  w_buf = (bf16*)d_out + NELT;
  float* out   = (float*)d_out;

  convert_kernel<<<dim3(12352), 256, 0, stream>>>(x, Wr, Wv, Ww, Wo, Wk, x_c, W_c, wks);
  proj_kernel<<<dim3(1536), 256, 0, stream>>>(x_c, W_c, r_buf, v_so, w_buf);
  ksum_kernel<<<dim3(BB * TT), 256, 0, stream>>>(x_c, wks, ksum);
  scanA_kernel<<<dim3(64, 16), 256, 0, stream>>>(v_so, w_buf, ksum, Pbuf, Abuf);
  scanB_kernel<<<dim3(16), 256, 0, stream>>>(Pbuf, Abuf);
  scanC_kernel<<<dim3(64, 16), 256, 0, stream>>>(r_buf, v_so, w_buf, ksum, Abuf);
  rmsnorm_inplace<<<dim3(BB * TT), 256, 0, stream>>>(v_so);
  out_gemm_kernel<<<dim3(512), 256, 0, stream>>>(v_so, W_c + 3 * 1048576, out);
}